// Round 4
// baseline (83.949 us; speedup 1.0000x reference)
//
#include <hip/hip_runtime.h>

#define NN 8192
#define DD 128
#define BR 128          // anchors per block
#define BC 128          // cols per LDS tile
#define NC 8            // column chunks (grid.y)
#define CPC (NN / NC)   // 1024 cols per chunk
#define NT (CPC / BC)   // 8 tiles per block
#define NCLS 100
#define NCH (NC * 4)    // partial chunks per row (4 waves x NC)

typedef short bf16x8v __attribute__((ext_vector_type(8)));
typedef float f32x4  __attribute__((ext_vector_type(4)));

constexpr float SSCALE  = 3.7982825265208916f; // sqrt((1/T)*log2(e))
constexpr float LN2     = 0.6931471805599453f;
constexpr float NEG_BIG = -1.0e30f;
constexpr float M_INIT  = -3.0e38f;

// ---------------- kernel 1: fp32 -> bf16 (RNE), pre-scaled by sqrt(SCALE2) ----------------
__global__ __launch_bounds__(256) void k_convert(const float* __restrict__ z,
                                                 unsigned short* __restrict__ zb) {
  int i = blockIdx.x * blockDim.x + threadIdx.x;
  const float4 v = reinterpret_cast<const float4*>(z)[i];
  auto cvt = [](float f) -> unsigned short {
    unsigned u = __float_as_uint(f);
    unsigned r = (u + 0x7fffu + ((u >> 16) & 1u)) >> 16;
    return (unsigned short)r;
  };
  ushort4 o;
  o.x = cvt(v.x * SSCALE); o.y = cvt(v.y * SSCALE);
  o.z = cvt(v.z * SSCALE); o.w = cvt(v.w * SSCALE);
  reinterpret_cast<ushort4*>(zb)[i] = o;
}

// ---- async global->LDS staging of one 128x128 bf16 tile ----
__device__ __forceinline__ void stage_tile(const unsigned short* __restrict__ zb,
                                           int gc0, unsigned short* __restrict__ bufc,
                                           int tid) {
#pragma unroll
  for (int q = 0; q < 8; ++q) {
    int c = q * 256 + tid;          // 16B chunk index, 2048 total
    int r = c >> 4;                 // row within tile
    int w = c & 15;                 // 16B slot within row
    int wsrc = w ^ (r & 7);         // inverse swizzle (XOR involution)
    const unsigned short* g = zb + ((size_t)(gc0 + r) << 7) + (wsrc << 3);
    __builtin_amdgcn_global_load_lds(
        (const __attribute__((address_space(1))) void*)(uintptr_t)g,
        (__attribute__((address_space(3))) void*)(unsigned)(uintptr_t)(bufc + (c << 3)),
        16, 0, 0);
  }
}

// ---------------- per-tile pure LSE epilogue ----------------
template<bool HD>
__device__ __forceinline__ void tile_lse(const f32x4 (&acc)[8][2], int w, int lr, int lg,
                                         float (&m)[8], float (&s)[8]) {
#pragma unroll
  for (int t = 0; t < 8; ++t) {
    float x[8];
#pragma unroll
    for (int st = 0; st < 2; ++st) {
#pragma unroll
      for (int r = 0; r < 4; ++r) {
        float v = acc[t][st][r];
        if (HD) {
          bool dg = (t * 16 + lr) == (w * 32 + st * 16 + lg * 4 + r);
          v = dg ? NEG_BIG : v;
        }
        x[st * 4 + r] = v;
      }
    }
    float tm = fmaxf(fmaxf(fmaxf(x[0], x[1]), fmaxf(x[2], x[3])),
                     fmaxf(fmaxf(x[4], x[5]), fmaxf(x[6], x[7])));
    float mn = fmaxf(m[t], tm);
    float e = ((exp2f(x[0] - mn) + exp2f(x[1] - mn)) + (exp2f(x[2] - mn) + exp2f(x[3] - mn)))
            + ((exp2f(x[4] - mn) + exp2f(x[5] - mn)) + (exp2f(x[6] - mn) + exp2f(x[7] - mn)));
    s[t] = fmaf(s[t], exp2f(m[t] - mn), e);
    m[t] = mn;
  }
}

// ---------------- kernel 2: Gram + online LSE (no label logic) ----------------
// 4 waves split the tile's 128 cols (32 each); each wave covers ALL 128 anchors (t=0..7).
__global__ __launch_bounds__(256, 2) void k_main(const unsigned short* __restrict__ zb,
                                                 float2* __restrict__ partials) {
  __shared__ unsigned short lds_a[2][BC * DD];   // 2 x 32KB

  const int tid  = threadIdx.x;
  const int lane = tid & 63;
  const int w    = tid >> 6;
  const int lr = lane & 15, lg = lane >> 4;
  const int rx = lr & 7;
  const int rowbase = blockIdx.x * BR;
  const int cb      = blockIdx.y;
  const int cStart  = cb * CPC;
  const int colbase = w * 32;

  // hoisted anchor (B) fragments: 8 t-subtiles x 4 K-steps = 128 VGPR
  bf16x8v bfr[8][4];
#pragma unroll
  for (int t = 0; t < 8; ++t) {
    int row = rowbase + t * 16 + lr;
#pragma unroll
    for (int ks = 0; ks < 4; ++ks)
      bfr[t][ks] = *reinterpret_cast<const bf16x8v*>(zb + (size_t)row * DD + ks * 32 + lg * 8);
  }

  stage_tile(zb, cStart, lds_a[0], tid);

  int woff[4];
#pragma unroll
  for (int ks = 0; ks < 4; ++ks) woff[ks] = ((ks * 4 + lg) ^ rx) << 3;

  float m[8], s[8];
#pragma unroll
  for (int t = 0; t < 8; ++t) { m[t] = M_INIT; s[t] = 0.f; }

  __syncthreads();

  int cur = 0;
  for (int tt = 0; tt < NT; ++tt) {
    const int c0 = cStart + tt * BC;
    if (tt + 1 < NT) stage_tile(zb, c0 + BC, lds_a[cur ^ 1], tid);

    const unsigned short* bufc = lds_a[cur];
    f32x4 acc[8][2];
#pragma unroll
    for (int st = 0; st < 2; ++st) {
      const unsigned short* rp = bufc + (colbase + st * 16 + lr) * DD;
      bf16x8v a0 = *reinterpret_cast<const bf16x8v*>(rp + woff[0]);
      bf16x8v a1 = *reinterpret_cast<const bf16x8v*>(rp + woff[1]);
      bf16x8v a2 = *reinterpret_cast<const bf16x8v*>(rp + woff[2]);
      bf16x8v a3 = *reinterpret_cast<const bf16x8v*>(rp + woff[3]);
#pragma unroll
      for (int t = 0; t < 8; ++t) {
        f32x4 a = (f32x4){0.f, 0.f, 0.f, 0.f};
        a = __builtin_amdgcn_mfma_f32_16x16x32_bf16(a0, bfr[t][0], a, 0, 0, 0);
        a = __builtin_amdgcn_mfma_f32_16x16x32_bf16(a1, bfr[t][1], a, 0, 0, 0);
        a = __builtin_amdgcn_mfma_f32_16x16x32_bf16(a2, bfr[t][2], a, 0, 0, 0);
        a = __builtin_amdgcn_mfma_f32_16x16x32_bf16(a3, bfr[t][3], a, 0, 0, 0);
        acc[t][st] = a;
      }
    }

    if (c0 == rowbase) tile_lse<true >(acc, w, lr, lg, m, s);
    else               tile_lse<false>(acc, w, lr, lg, m, s);

    __syncthreads();
    cur ^= 1;
  }

  // merge the 4 lane-groups (xor 16, 32)
#pragma unroll
  for (int off = 16; off <= 32; off <<= 1) {
#pragma unroll
    for (int t = 0; t < 8; ++t) {
      float mo = __shfl_xor(m[t], off);
      float so = __shfl_xor(s[t], off);
      float mn = fmaxf(m[t], mo);
      s[t] = s[t] * exp2f(m[t] - mn) + so * exp2f(mo - mn);
      m[t] = mn;
    }
  }
  if (lg == 0) {
#pragma unroll
    for (int t = 0; t < 8; ++t)
      partials[(size_t)(cb * 4 + w) * NN + rowbase + t * 16 + lr] = make_float2(m[t], s[t]);
  }
}

// ---------------- kernel 3: per-class exact correction + per-class loss sum ----------------
// Block per class. Rebuilds matched-pair v via the IDENTICAL MFMA chain (bitwise-equal),
// applies s -= 0.5*sum(exp2(v-m)), computes con exactly, reduces loss per class.
__global__ __launch_bounds__(256) void k_corr(const unsigned short* __restrict__ zb,
                                              const int* __restrict__ labels,
                                              const float2* __restrict__ partials,
                                              float* __restrict__ clsum) {
  const int c = blockIdx.x;
  const int tid = threadIdx.x, lane = tid & 63, w = tid >> 6;
  __shared__ int rows[128];
  __shared__ float rowm[128], rowss[128];
  __shared__ int wavecnt[4];
  __shared__ float clpart[4];

  // deterministic ordered compaction of this class's row indices
  int base = 0;
  for (int rd = 0; rd < NN / 256; ++rd) {
    int idx = rd * 256 + tid;
    bool mt = (labels[idx] == c);
    unsigned long long mask = __ballot(mt);
    int wc = __popcll(mask);
    if (lane == 0) wavecnt[w] = wc;
    __syncthreads();
    int off = base;
    for (int ww = 0; ww < 4; ++ww) if (ww < w) off += wavecnt[ww];
    int tot = wavecnt[0] + wavecnt[1] + wavecnt[2] + wavecnt[3];
    if (mt) {
      int p = off + __popcll(mask & ((1ull << lane) - 1ull));
      if (p < 128) rows[p] = idx;
    }
    base += tot;
    __syncthreads();
  }
  int n = base > 128 ? 128 : base;
  if (n < 2) { if (tid == 0) clsum[c] = 0.f; return; }

  // merge the 32 chunk-partials per row
  for (int r = tid; r < n; r += 256) {
    int row = rows[r];
    float m = M_INIT, s = 0.f;
    for (int ch = 0; ch < NCH; ++ch) {
      float2 p = partials[(size_t)ch * NN + row];
      float mn = fmaxf(m, p.x);
      s = s * exp2f(m - mn) + p.y * exp2f(p.x - mn);
      m = mn;
    }
    rowm[r] = m; rowss[r] = s;
  }
  __syncthreads();

  const int lr = lane & 15, lg = lane >> 4;
  const int NB = (n + 15) >> 4;
  float wloss = 0.f;
  for (int ab = w; ab < NB; ab += 4) {
    int a = ab * 16 + lr;
    bool aok = a < n;
    int ga = rows[aok ? a : 0];
    bf16x8v bf[4];
#pragma unroll
    for (int ks = 0; ks < 4; ++ks)
      bf[ks] = *reinterpret_cast<const bf16x8v*>(zb + (size_t)ga * DD + ks * 32 + lg * 8);
    float ma = aok ? rowm[a] : 0.f;
    float sumv = 0.f, sume = 0.f;
    for (int bb = 0; bb < NB; ++bb) {
      int bi = bb * 16 + lr;
      int gb = rows[bi < n ? bi : 0];
      bf16x8v af[4];
#pragma unroll
      for (int ks = 0; ks < 4; ++ks)
        af[ks] = *reinterpret_cast<const bf16x8v*>(zb + (size_t)gb * DD + ks * 32 + lg * 8);
      f32x4 acc = (f32x4){0.f, 0.f, 0.f, 0.f};
      acc = __builtin_amdgcn_mfma_f32_16x16x32_bf16(af[0], bf[0], acc, 0, 0, 0);
      acc = __builtin_amdgcn_mfma_f32_16x16x32_bf16(af[1], bf[1], acc, 0, 0, 0);
      acc = __builtin_amdgcn_mfma_f32_16x16x32_bf16(af[2], bf[2], acc, 0, 0, 0);
      acc = __builtin_amdgcn_mfma_f32_16x16x32_bf16(af[3], bf[3], acc, 0, 0, 0);
#pragma unroll
      for (int r = 0; r < 4; ++r) {
        int b = bb * 16 + lg * 4 + r;
        bool ok = (b < n) && (b != a);
        float v = acc[r];
        sumv += ok ? v : 0.f;
        float e = exp2f(v - ma);
        sume += ok ? e : 0.f;
      }
    }
#pragma unroll
    for (int off = 16; off <= 32; off <<= 1) {
      sumv += __shfl_xor(sumv, off);
      sume += __shfl_xor(sume, off);
    }
    if (lg == 0 && aok) {
      float sp = rowss[a] - 0.5f * sume;            // apply 0.5 weight to matches
      wloss += LN2 * (ma + log2f(sp)) - LN2 * sumv / (float)(n - 1);
    }
  }
#pragma unroll
  for (int off = 32; off >= 1; off >>= 1) wloss += __shfl_xor(wloss, off);
  if (lane == 0) clpart[w] = wloss;
  __syncthreads();
  if (tid == 0) clsum[c] = (clpart[0] + clpart[1]) + (clpart[2] + clpart[3]);
}

// ---------------- kernel 4: final sum over classes ----------------
__global__ __launch_bounds__(128) void k_final(const float* __restrict__ clsum,
                                               float* __restrict__ out) {
  const int tid = threadIdx.x;
  float v = (tid < NCLS) ? clsum[tid] : 0.f;
#pragma unroll
  for (int off = 32; off >= 1; off >>= 1) v += __shfl_xor(v, off);
  __shared__ float t2[2];
  if ((tid & 63) == 0) t2[tid >> 6] = v;
  __syncthreads();
  if (tid == 0) out[0] = (t2[0] + t2[1]) * (1.0f / (float)NN);
}

extern "C" void kernel_launch(void* const* d_in, const int* in_sizes, int n_in,
                              void* d_out, int out_size, void* d_ws, size_t ws_size,
                              hipStream_t stream) {
  const float* z      = (const float*)d_in[0];
  const int*   labels = (const int*)d_in[1];

  char* ws = (char*)d_ws;
  unsigned short* zb = (unsigned short*)ws;                               // 2 MB
  float2* partials   = (float2*)(ws + (size_t)NN * DD * 2);               // 32*NN*8 = 2 MB
  float*  clsum      = (float*)(ws + (size_t)NN * DD * 2 + (size_t)NCH * NN * 8);

  hipLaunchKernelGGL(k_convert, dim3(NN * DD / 4 / 256), dim3(256), 0, stream, z, zb);
  hipLaunchKernelGGL(k_main,    dim3(NN / BR, NC), dim3(256), 0, stream, zb, partials);
  hipLaunchKernelGGL(k_corr,    dim3(NCLS), dim3(256), 0, stream, zb, labels, partials, clsum);
  hipLaunchKernelGGL(k_final,   dim3(1), dim3(128), 0, stream, clsum, (float*)d_out);
}

// Round 5
// 57.767 us; speedup vs baseline: 1.4532x; 1.4532x over previous
//
#include <hip/hip_runtime.h>

#define NN 8192
#define DD 128
#define BR 128          // anchors per block
#define BC 64           // cols per LDS tile
#define NCLS 100
#define CAPR 192        // max rows per class

typedef short bf16x8v __attribute__((ext_vector_type(8)));
typedef float f32x4  __attribute__((ext_vector_type(4)));

constexpr float SSCALE  = 3.7982825265208916f; // sqrt((1/T)*log2(e))
constexpr float LN2     = 0.6931471805599453f;
constexpr float NEG_BIG = -1.0e30f;
constexpr float M_INIT  = -3.0e38f;

__device__ __forceinline__ float ex2(float x) { return __builtin_amdgcn_exp2f(x); }

// ---------------- kernel 1: fp32 -> bf16 (RNE), pre-scaled by sqrt(SCALE2) ----------------
__global__ __launch_bounds__(256) void k_convert(const float* __restrict__ z,
                                                 unsigned short* __restrict__ zb) {
  int i = blockIdx.x * blockDim.x + threadIdx.x;
  const float4 v = reinterpret_cast<const float4*>(z)[i];
  auto cvt = [](float f) -> unsigned short {
    unsigned u = __float_as_uint(f);
    unsigned r = (u + 0x7fffu + ((u >> 16) & 1u)) >> 16;
    return (unsigned short)r;
  };
  ushort4 o;
  o.x = cvt(v.x * SSCALE); o.y = cvt(v.y * SSCALE);
  o.z = cvt(v.z * SSCALE); o.w = cvt(v.w * SSCALE);
  reinterpret_cast<ushort4*>(zb)[i] = o;
}

// ---- async global->LDS staging of one 64x128 bf16 tile (16KB) ----
__device__ __forceinline__ void stage_tile(const unsigned short* __restrict__ zb,
                                           int gc0, unsigned short* __restrict__ bufc,
                                           int tid) {
#pragma unroll
  for (int q = 0; q < 4; ++q) {
    int c = q * 256 + tid;          // 16B chunk index, 1024 total
    int r = c >> 4;                 // row within tile (0..63)
    int w = c & 15;                 // 16B slot within row
    int wsrc = w ^ (r & 7);         // inverse swizzle (XOR involution)
    const unsigned short* g = zb + ((size_t)(gc0 + r) << 7) + (wsrc << 3);
    __builtin_amdgcn_global_load_lds(
        (const __attribute__((address_space(1))) void*)(uintptr_t)g,
        (__attribute__((address_space(3))) void*)(unsigned)(uintptr_t)(bufc + (c << 3)),
        16, 0, 0);
  }
}

// ---------------- per-tile pure LSE epilogue (label-free) ----------------
template<bool HD>
__device__ __forceinline__ void tile_lse(const f32x4 (&acc)[2][4], int aloc0, int c0r,
                                         int lg, float (&m)[2], float (&s)[2]) {
#pragma unroll
  for (int t = 0; t < 2; ++t) {
    float x[16];
#pragma unroll
    for (int st = 0; st < 4; ++st) {
#pragma unroll
      for (int r = 0; r < 4; ++r) {
        float v = acc[t][st][r];
        if (HD) {
          bool dg = (aloc0 + t * 16) == (c0r + st * 16 + lg * 4 + r);
          v = dg ? NEG_BIG : v;
        }
        x[st * 4 + r] = v;
      }
    }
    float m8[8];
#pragma unroll
    for (int k = 0; k < 8; ++k) m8[k] = fmaxf(x[k], x[k + 8]);
    float ma = fmaxf(fmaxf(m8[0], m8[1]), fmaxf(m8[2], m8[3]));
    float mb = fmaxf(fmaxf(m8[4], m8[5]), fmaxf(m8[6], m8[7]));
    float mn = fmaxf(m[t], fmaxf(ma, mb));
    float e0 = 0.f, e1 = 0.f, e2 = 0.f, e3 = 0.f;
#pragma unroll
    for (int k = 0; k < 16; k += 4) {
      e0 += ex2(x[k + 0] - mn);
      e1 += ex2(x[k + 1] - mn);
      e2 += ex2(x[k + 2] - mn);
      e3 += ex2(x[k + 3] - mn);
    }
    s[t] = fmaf(s[t], ex2(m[t] - mn), (e0 + e1) + (e2 + e3));
    m[t] = mn;
  }
}

// ---------------- kernel 2: Gram + online LSE ----------------
// Wave w owns 32 anchors (rowbase + w*32 .. +32) x ALL 64 tile cols.
__global__ __launch_bounds__(256) void k_main(const unsigned short* __restrict__ zb,
                                              float2* __restrict__ partials,
                                              int cpc, int nt) {
  __shared__ unsigned short lds_a[2][BC * DD];   // 2 x 16KB

  const int tid  = threadIdx.x;
  const int lane = tid & 63;
  const int w    = tid >> 6;
  const int lr = lane & 15, lg = lane >> 4;
  const int rx = lr & 7;
  const int rowbase = blockIdx.x * BR;
  const int cb      = blockIdx.y;
  const int cStart  = cb * cpc;
  const int aloc0   = w * 32 + lr;

  // hoisted anchor (B) fragments: 2 t-subtiles x 4 K-steps = 32 VGPR
  bf16x8v bfr[2][4];
#pragma unroll
  for (int t = 0; t < 2; ++t) {
    int row = rowbase + w * 32 + t * 16 + lr;
#pragma unroll
    for (int ks = 0; ks < 4; ++ks)
      bfr[t][ks] = *reinterpret_cast<const bf16x8v*>(zb + (size_t)row * DD + ks * 32 + lg * 8);
  }

  stage_tile(zb, cStart, lds_a[0], tid);

  int woff[4];
#pragma unroll
  for (int ks = 0; ks < 4; ++ks) woff[ks] = ((ks * 4 + lg) ^ rx) << 3;

  float m[2] = {M_INIT, M_INIT}, s[2] = {0.f, 0.f};
  __syncthreads();

  int cur = 0;
  for (int tt = 0; tt < nt; ++tt) {
    const int c0 = cStart + tt * BC;
    if (tt + 1 < nt) stage_tile(zb, c0 + BC, lds_a[cur ^ 1], tid);

    const unsigned short* bufc = lds_a[cur];
    f32x4 acc[2][4];
#pragma unroll
    for (int st = 0; st < 4; ++st) {
      const unsigned short* rp = bufc + (st * 16 + lr) * DD;
      bf16x8v a0 = *reinterpret_cast<const bf16x8v*>(rp + woff[0]);
      bf16x8v a1 = *reinterpret_cast<const bf16x8v*>(rp + woff[1]);
      bf16x8v a2 = *reinterpret_cast<const bf16x8v*>(rp + woff[2]);
      bf16x8v a3 = *reinterpret_cast<const bf16x8v*>(rp + woff[3]);
#pragma unroll
      for (int t = 0; t < 2; ++t) {
        f32x4 a = (f32x4){0.f, 0.f, 0.f, 0.f};
        a = __builtin_amdgcn_mfma_f32_16x16x32_bf16(a0, bfr[t][0], a, 0, 0, 0);
        a = __builtin_amdgcn_mfma_f32_16x16x32_bf16(a1, bfr[t][1], a, 0, 0, 0);
        a = __builtin_amdgcn_mfma_f32_16x16x32_bf16(a2, bfr[t][2], a, 0, 0, 0);
        a = __builtin_amdgcn_mfma_f32_16x16x32_bf16(a3, bfr[t][3], a, 0, 0, 0);
        acc[t][st] = a;
      }
    }

    // wave's diagonal falls in exactly one tile: c0 == rowbase + (w>=2 ? 64 : 0)
    if (c0 == rowbase + ((w >> 1) << 6))
      tile_lse<true >(acc, aloc0, c0 - rowbase, lg, m, s);
    else
      tile_lse<false>(acc, aloc0, 0, lg, m, s);

    __syncthreads();
    cur ^= 1;
  }

  // merge the 4 lane-groups (xor 16, 32)
#pragma unroll
  for (int off = 16; off <= 32; off <<= 1) {
#pragma unroll
    for (int t = 0; t < 2; ++t) {
      float mo = __shfl_xor(m[t], off);
      float so = __shfl_xor(s[t], off);
      float mn = fmaxf(m[t], mo);
      s[t] = s[t] * ex2(m[t] - mn) + so * ex2(mo - mn);
      m[t] = mn;
    }
  }
  if (lg == 0) {
#pragma unroll
    for (int t = 0; t < 2; ++t)
      partials[(size_t)cb * NN + rowbase + w * 32 + t * 16 + lr] = make_float2(m[t], s[t]);
  }
}

// ---------------- kernel 3: per-class exact correction + per-class loss ----------------
__global__ __launch_bounds__(256) void k_corr(const unsigned short* __restrict__ zb,
                                              const int* __restrict__ labels,
                                              const float2* __restrict__ partials,
                                              float* __restrict__ clsum, int nch) {
  const int c = blockIdx.x;
  const int tid = threadIdx.x, lane = tid & 63, w = tid >> 6;
  __shared__ int rows[CAPR];
  __shared__ float rowm[CAPR], rowss[CAPR];
  __shared__ int nsh;
  __shared__ float clpart[4];

  // wave-synchronous deterministic compaction (wave 0 only, no barriers inside)
  if (w == 0) {
    int base = 0;
    for (int rd = 0; rd < NN / 256; ++rd) {
      int4 v = *reinterpret_cast<const int4*>(labels + rd * 256 + lane * 4);
      int labq[4] = {v.x, v.y, v.z, v.w};
#pragma unroll
      for (int q = 0; q < 4; ++q) {
        bool mt = (labq[q] == c);
        unsigned long long mask = __ballot(mt);
        if (mt) {
          int p = base + __popcll(mask & ((1ull << lane) - 1ull));
          if (p < CAPR) rows[p] = rd * 256 + lane * 4 + q;
        }
        base += __popcll(mask);
      }
    }
    if (lane == 0) nsh = base < CAPR ? base : CAPR;
  }
  __syncthreads();
  const int n = nsh;
  if (n < 2) { if (tid == 0) clsum[c] = 0.f; return; }

  // merge the nch chunk-partials per row
  for (int r = tid; r < n; r += 256) {
    int row = rows[r];
    float m = M_INIT, s = 0.f;
    for (int ch = 0; ch < nch; ++ch) {
      float2 p = partials[(size_t)ch * NN + row];
      float mn = fmaxf(m, p.x);
      s = s * ex2(m - mn) + p.y * ex2(p.x - mn);
      m = mn;
    }
    rowm[r] = m; rowss[r] = s;
  }
  __syncthreads();

  const int lr = lane & 15, lg = lane >> 4;
  const int NB = (n + 15) >> 4;
  float wloss = 0.f;
  for (int ab = w; ab < NB; ab += 4) {
    int a = ab * 16 + lr;
    bool aok = a < n;
    int ga = rows[aok ? a : 0];
    bf16x8v bf[4];
#pragma unroll
    for (int ks = 0; ks < 4; ++ks)
      bf[ks] = *reinterpret_cast<const bf16x8v*>(zb + (size_t)ga * DD + ks * 32 + lg * 8);
    float ma = aok ? rowm[a] : 0.f;
    float sumv = 0.f, sume = 0.f;
    for (int bb = 0; bb < NB; ++bb) {
      int bi = bb * 16 + lr;
      int gb = rows[bi < n ? bi : 0];
      bf16x8v af[4];
#pragma unroll
      for (int ks = 0; ks < 4; ++ks)
        af[ks] = *reinterpret_cast<const bf16x8v*>(zb + (size_t)gb * DD + ks * 32 + lg * 8);
      f32x4 acc = (f32x4){0.f, 0.f, 0.f, 0.f};
      acc = __builtin_amdgcn_mfma_f32_16x16x32_bf16(af[0], bf[0], acc, 0, 0, 0);
      acc = __builtin_amdgcn_mfma_f32_16x16x32_bf16(af[1], bf[1], acc, 0, 0, 0);
      acc = __builtin_amdgcn_mfma_f32_16x16x32_bf16(af[2], bf[2], acc, 0, 0, 0);
      acc = __builtin_amdgcn_mfma_f32_16x16x32_bf16(af[3], bf[3], acc, 0, 0, 0);
#pragma unroll
      for (int r = 0; r < 4; ++r) {
        int b = bb * 16 + lg * 4 + r;
        bool ok = (b < n) && (b != a);
        float v = acc[r];
        sumv += ok ? v : 0.f;
        float e = ex2(v - ma);
        sume += ok ? e : 0.f;
      }
    }
#pragma unroll
    for (int off = 16; off <= 32; off <<= 1) {
      sumv += __shfl_xor(sumv, off);
      sume += __shfl_xor(sume, off);
    }
    if (lg == 0 && aok) {
      float sp = rowss[a] - 0.5f * sume;            // apply 0.5 weight to matches
      wloss += LN2 * (ma + log2f(sp)) - LN2 * sumv / (float)(n - 1);
    }
  }
#pragma unroll
  for (int off = 32; off >= 1; off >>= 1) wloss += __shfl_xor(wloss, off);
  if (lane == 0) clpart[w] = wloss;
  __syncthreads();
  if (tid == 0) clsum[c] = (clpart[0] + clpart[1]) + (clpart[2] + clpart[3]);
}

// ---------------- kernel 4: final sum over classes ----------------
__global__ __launch_bounds__(128) void k_final(const float* __restrict__ clsum,
                                               float* __restrict__ out) {
  const int tid = threadIdx.x;
  float v = (tid < NCLS) ? clsum[tid] : 0.f;
#pragma unroll
  for (int off = 32; off >= 1; off >>= 1) v += __shfl_xor(v, off);
  __shared__ float t2[2];
  if ((tid & 63) == 0) t2[tid >> 6] = v;
  __syncthreads();
  if (tid == 0) out[0] = (t2[0] + t2[1]) * (1.0f / (float)NN);
}

extern "C" void kernel_launch(void* const* d_in, const int* in_sizes, int n_in,
                              void* d_out, int out_size, void* d_ws, size_t ws_size,
                              hipStream_t stream) {
  const float* z      = (const float*)d_in[0];
  const int*   labels = (const int*)d_in[1];

  const int NC  = 16;            // column chunks (grid.y)
  const int cpc = NN / NC;       // 512
  const int nt  = cpc / BC;      // 8

  char* ws = (char*)d_ws;
  unsigned short* zb = (unsigned short*)ws;                                 // 2 MB
  float2* partials   = (float2*)(ws + (size_t)NN * DD * 2);                 // NC*NN*8 = 1 MB
  float*  clsum      = (float*)(ws + (size_t)NN * DD * 2 + (size_t)NC * NN * 8);

  hipLaunchKernelGGL(k_convert, dim3(NN * DD / 4 / 256), dim3(256), 0, stream, z, zb);
  hipLaunchKernelGGL(k_main,    dim3(NN / BR, NC), dim3(256), 0, stream, zb, partials, cpc, nt);
  hipLaunchKernelGGL(k_corr,    dim3(NCLS), dim3(256), 0, stream, zb, labels, partials, clsum, NC);
  hipLaunchKernelGGL(k_final,   dim3(1), dim3(128), 0, stream, clsum, (float*)d_out);
}